// Round 2
// baseline (26079.773 us; speedup 1.0000x reference)
//
#include <hip/hip_runtime.h>
#include <cstdint>
#include <cstddef>

#define T_STEPS 100
#define IN_DIM  140
#define HDIM    256
#define G4      1024
#define RB      16
#define HB      8            // rows per half
#define NTHR    512
#define BTOT    4096
#define NBLK    (BTOT/RB)    // 256 blocks
#define STR     20           // padded LDS row stride (floats): conflict-free b128

#define K0      (IN_DIM + HDIM)   // 396
#define SZ_WT0  (K0*G4)           // 405504
#define K1      (2*HDIM)          // 512
#define SZ_WT1  (K1*G4)           // 524288
#define SZ_WTA  (HDIM*HDIM)       // 65536
#define OFF_WT0 0
#define OFF_WT1 (OFF_WT0 + SZ_WT0)
#define OFF_WTA (OFF_WT1 + SZ_WT1)
#define OFF_B0  (OFF_WTA + SZ_WTA)
#define OFF_B1  (OFF_B0 + G4)
#define WS_FLOATS (OFF_B1 + G4)   // ~3.99 MB

__device__ __forceinline__ float sigmoidf_(float x) {
    return 1.0f / (1.0f + __expf(-x));
}
__device__ __forceinline__ float tanhf_(float x) {
    return 1.0f - 2.0f / (__expf(2.0f * x) + 1.0f);
}

__device__ __forceinline__ void load8(float* d, const float* s) {
    const float4* p = (const float4*)s;
    float4 a = p[0], b = p[1];
    d[0]=a.x; d[1]=a.y; d[2]=a.z; d[3]=a.w;
    d[4]=b.x; d[5]=b.y; d[6]=b.z; d[7]=b.w;
}

// Transposed gate-packed weights + folded biases (same layout as R1).
__global__ void prep(const float* __restrict__ Wih0, const float* __restrict__ Whh0,
                     const float* __restrict__ bih0, const float* __restrict__ bhh0,
                     const float* __restrict__ Wih1, const float* __restrict__ Whh1,
                     const float* __restrict__ bih1, const float* __restrict__ bhh1,
                     const float* __restrict__ Wa1,  float* __restrict__ ws)
{
    int idx = blockIdx.x * blockDim.x + threadIdx.x;
    if (idx >= WS_FLOATS) return;
    float v;
    if (idx < OFF_WT1) {
        int l = idx;
        int g = l & 3, j4 = (l >> 2) & 255, k = l >> 10;
        int j = g * HDIM + j4;
        v = (k < IN_DIM) ? Wih0[j * IN_DIM + k] : Whh0[j * HDIM + (k - IN_DIM)];
    } else if (idx < OFF_WTA) {
        int l = idx - OFF_WT1;
        int g = l & 3, j4 = (l >> 2) & 255, k = l >> 10;
        int j = g * HDIM + j4;
        v = (k < HDIM) ? Wih1[j * HDIM + k] : Whh1[j * HDIM + (k - HDIM)];
    } else if (idx < OFF_B0) {
        int l = idx - OFF_WTA;
        int j = l & 255, k = l >> 8;
        v = Wa1[j * HDIM + k];
    } else if (idx < OFF_B1) {
        int j = idx - OFF_B0;
        v = bih0[j] + bhh0[j];
    } else {
        int j = idx - OFF_B1;
        v = bih1[j] + bhh1[j];
    }
    ws[idx] = v;
}

__global__ __launch_bounds__(NTHR, 2) void lstm_main(
    const float* __restrict__ x, const float* __restrict__ ws,
    const float* __restrict__ Wa2, const float* __restrict__ ba1,
    const float* __restrict__ ba2, float* __restrict__ out)
{
    __shared__ __align__(16) float xs [IN_DIM][STR];
    __shared__ __align__(16) float h0s[HDIM][STR];
    __shared__ __align__(16) float h1s[HDIM][STR];
    __shared__ __align__(16) float red[8][HB];

    const int tid  = threadIdx.x;
    const int jh   = tid & 255;   // hidden unit owned by this thread
    const int half = tid >> 8;    // which 8 batch rows
    const int lane = tid & 63;
    const int wv   = tid >> 6;    // 0..7
    const int row0 = blockIdx.x * RB;
    const int co   = half * HB;   // column offset in LDS tiles

    const float4* W0 = (const float4*)(ws + OFF_WT0);
    const float4* W1 = (const float4*)(ws + OFF_WT1);
    const float*  WA = ws + OFF_WTA;
    const float*  b0 = ws + OFF_B0;
    const float*  b1 = ws + OFF_B1;

    float c0[HB], c1[HB];
    #pragma unroll
    for (int b = 0; b < HB; b++) { c0[b] = 0.f; c1[b] = 0.f; }
    for (int i = tid; i < HDIM * STR; i += NTHR) {
        (&h0s[0][0])[i] = 0.f;
        (&h1s[0][0])[i] = 0.f;
    }

    const float bi0 = b0[jh], bf0 = b0[jh + 256], bg0 = b0[jh + 512], bo0 = b0[jh + 768];
    const float bi1 = b1[jh], bf1 = b1[jh + 256], bg1 = b1[jh + 512], bo1 = b1[jh + 768];
    const float wa2  = Wa2[jh];
    const float ba1v = ba1[jh];
    const float ba2v = ba2[0];

    __syncthreads();

    for (int t = 0; t < T_STEPS; t++) {
        // ---- stage x_t into LDS (k-major, padded) ----
        for (int i = tid; i < IN_DIM * RB; i += NTHR) {
            int b = i / IN_DIM, k = i - b * IN_DIM;
            xs[k][b] = x[(size_t)(row0 + b) * (T_STEPS * IN_DIM) + (size_t)t * IN_DIM + k];
        }
        __syncthreads();

        // ---- layer 0 gates ----
        float ai[HB], af[HB], ag[HB], ao[HB];
        #pragma unroll
        for (int b = 0; b < HB; b++) { ai[b] = bi0; af[b] = bf0; ag[b] = bg0; ao[b] = bo0; }

        #pragma unroll 4
        for (int k = 0; k < IN_DIM; k++) {
            float4 w = W0[k * HDIM + jh];
            float xq[HB]; load8(xq, &xs[k][co]);
            #pragma unroll
            for (int b = 0; b < HB; b++) {
                ai[b] = fmaf(w.x, xq[b], ai[b]);
                af[b] = fmaf(w.y, xq[b], af[b]);
                ag[b] = fmaf(w.z, xq[b], ag[b]);
                ao[b] = fmaf(w.w, xq[b], ao[b]);
            }
        }
        #pragma unroll 4
        for (int k = 0; k < HDIM; k++) {
            float4 w = W0[(IN_DIM + k) * HDIM + jh];
            float xq[HB]; load8(xq, &h0s[k][co]);
            #pragma unroll
            for (int b = 0; b < HB; b++) {
                ai[b] = fmaf(w.x, xq[b], ai[b]);
                af[b] = fmaf(w.y, xq[b], af[b]);
                ag[b] = fmaf(w.z, xq[b], ag[b]);
                ao[b] = fmaf(w.w, xq[b], ao[b]);
            }
        }

        float hn[HB];
        #pragma unroll
        for (int b = 0; b < HB; b++) {
            float ig = sigmoidf_(ai[b]);
            float fg = sigmoidf_(af[b]);
            float gg = tanhf_(ag[b]);
            float og = sigmoidf_(ao[b]);
            float c  = fmaf(fg, c0[b], ig * gg);
            c0[b] = c;
            hn[b] = og * tanhf_(c);
        }
        __syncthreads();   // all reads of old h0s done
        {
            float4 v0 = make_float4(hn[0], hn[1], hn[2], hn[3]);
            float4 v1 = make_float4(hn[4], hn[5], hn[6], hn[7]);
            float4* p = (float4*)&h0s[jh][co];
            p[0] = v0; p[1] = v1;
        }
        __syncthreads();   // new h0s visible

        // ---- layer 1 gates ----
        #pragma unroll
        for (int b = 0; b < HB; b++) { ai[b] = bi1; af[b] = bf1; ag[b] = bg1; ao[b] = bo1; }

        #pragma unroll 4
        for (int k = 0; k < HDIM; k++) {
            float4 w = W1[k * HDIM + jh];
            float xq[HB]; load8(xq, &h0s[k][co]);
            #pragma unroll
            for (int b = 0; b < HB; b++) {
                ai[b] = fmaf(w.x, xq[b], ai[b]);
                af[b] = fmaf(w.y, xq[b], af[b]);
                ag[b] = fmaf(w.z, xq[b], ag[b]);
                ao[b] = fmaf(w.w, xq[b], ao[b]);
            }
        }
        #pragma unroll 4
        for (int k = 0; k < HDIM; k++) {
            float4 w = W1[(HDIM + k) * HDIM + jh];
            float xq[HB]; load8(xq, &h1s[k][co]);
            #pragma unroll
            for (int b = 0; b < HB; b++) {
                ai[b] = fmaf(w.x, xq[b], ai[b]);
                af[b] = fmaf(w.y, xq[b], af[b]);
                ag[b] = fmaf(w.z, xq[b], ag[b]);
                ao[b] = fmaf(w.w, xq[b], ao[b]);
            }
        }

        #pragma unroll
        for (int b = 0; b < HB; b++) {
            float ig = sigmoidf_(ai[b]);
            float fg = sigmoidf_(af[b]);
            float gg = tanhf_(ag[b]);
            float og = sigmoidf_(ao[b]);
            float c  = fmaf(fg, c1[b], ig * gg);
            c1[b] = c;
            hn[b] = og * tanhf_(c);
        }
        __syncthreads();   // all reads of old h1s done
        {
            float4 v0 = make_float4(hn[0], hn[1], hn[2], hn[3]);
            float4 v1 = make_float4(hn[4], hn[5], hn[6], hn[7]);
            float4* p = (float4*)&h1s[jh][co];
            p[0] = v0; p[1] = v1;
        }
        __syncthreads();   // new h1s visible

        // ---- advantage MLP ----
        float ah[HB];
        #pragma unroll
        for (int b = 0; b < HB; b++) ah[b] = ba1v;
        #pragma unroll 4
        for (int k = 0; k < HDIM; k++) {
            float wk = WA[k * HDIM + jh];
            float xq[HB]; load8(xq, &h1s[k][co]);
            #pragma unroll
            for (int b = 0; b < HB; b++) ah[b] = fmaf(wk, xq[b], ah[b]);
        }
        #pragma unroll
        for (int b = 0; b < HB; b++) {
            float p = fmaxf(ah[b], 0.f) * wa2;
            #pragma unroll
            for (int m = 32; m >= 1; m >>= 1) p += __shfl_xor(p, m, 64);
            if (lane == 0) red[wv][b] = p;
        }
        __syncthreads();   // red ready
        if (tid < RB) {
            int hh = tid >> 3, b = tid & 7;
            float o = red[hh * 4 + 0][b] + red[hh * 4 + 1][b]
                    + red[hh * 4 + 2][b] + red[hh * 4 + 3][b] + ba2v;
            out[(size_t)t * BTOT + row0 + tid] = o;
        }
        // red is not rewritten until after 5 intervening barriers next step.
    }
}

extern "C" void kernel_launch(void* const* d_in, const int* in_sizes, int n_in,
                              void* d_out, int out_size, void* d_ws, size_t ws_size,
                              hipStream_t stream)
{
    const float* x    = (const float*)d_in[0];
    const float* Wih0 = (const float*)d_in[1];
    const float* Whh0 = (const float*)d_in[2];
    const float* bih0 = (const float*)d_in[3];
    const float* bhh0 = (const float*)d_in[4];
    const float* Wih1 = (const float*)d_in[5];
    const float* Whh1 = (const float*)d_in[6];
    const float* bih1 = (const float*)d_in[7];
    const float* bhh1 = (const float*)d_in[8];
    const float* Wa1  = (const float*)d_in[9];
    const float* ba1  = (const float*)d_in[10];
    const float* Wa2  = (const float*)d_in[11];
    const float* ba2  = (const float*)d_in[12];
    float* ws  = (float*)d_ws;
    float* out = (float*)d_out;

    hipLaunchKernelGGL(prep, dim3((WS_FLOATS + 255) / 256), dim3(256), 0, stream,
                       Wih0, Whh0, bih0, bhh0, Wih1, Whh1, bih1, bhh1, Wa1, ws);
    hipLaunchKernelGGL(lstm_main, dim3(NBLK), dim3(NTHR), 0, stream,
                       x, ws, Wa2, ba1, ba2, out);
}

// Round 3
// 12421.909 us; speedup vs baseline: 2.0995x; 2.0995x over previous
//
#include <hip/hip_runtime.h>
#include <cstdint>
#include <cstddef>

#define T_STEPS 100
#define IN_DIM  140
#define HDIM    256
#define BTOT    4096
#define NBLK    (BTOT/16)     // 256 blocks
#define NTHR    512           // 8 waves

typedef _Float16 f16;
typedef _Float16 f16x8 __attribute__((ext_vector_type(8)));
typedef float    f32x4 __attribute__((ext_vector_type(4)));

// K dims (padded to 32): gates0 K=416 (x 160 incl pad + h0 256), gates1 K=512, adv K=256
#define NS0 13
#define NS1 16
#define NSA 8
// fragment counts (f16 elements): frag = 64 lanes x 8 f16 = 512 elems = 1KB
#define E0 (NS0*64*512)       // 425984
#define E1 (NS1*64*512)       // 524288
#define EA (NSA*16*512)       // 65536
#define F16TOT (E0+E1+EA)     // 1015808 f16 = 2031616 B
#define EB 2048               // 2x1024 fp32 biases
#define PREP_TOT (F16TOT+EB)  // 1017856 = 3976*256

// LDS activation tile: cols 0-159 x(padded), 160-415 h0, 416-671 h1, 672-679 pad
#define ACOLS 680
#define H0COL 160
#define H1COL 416

__device__ __forceinline__ float sigmoidf_(float x) {
    return 1.0f / (1.0f + __expf(-x));
}
__device__ __forceinline__ float tanhf_(float x) {
    return 1.0f - 2.0f / (__expf(2.0f * x) + 1.0f);
}

// Pack weights into MFMA B-fragment order (fp16) + folded fp32 biases.
// Frag (ks, nt): lane l, elem e -> B[k = ks*32 + (l>>4)*8 + e][n = nt*16 + (l&15)]
// stored at wsf[(ks*NT + nt)*512 + l*8 + e].
__global__ void prep(const float* __restrict__ Wih0, const float* __restrict__ Whh0,
                     const float* __restrict__ bih0, const float* __restrict__ bhh0,
                     const float* __restrict__ Wih1, const float* __restrict__ Whh1,
                     const float* __restrict__ bih1, const float* __restrict__ bhh1,
                     const float* __restrict__ Wa1,  f16* __restrict__ wsf,
                     float* __restrict__ wsb)
{
    int idx = blockIdx.x * 256 + threadIdx.x;
    if (idx < E0) {
        int e = idx & 7, l = (idx >> 3) & 63, fi = idx >> 9;
        int nt = fi & 63, ks = fi >> 6;
        int k = ks * 32 + ((l >> 4) << 3) + e;
        int n = nt * 16 + (l & 15);
        float v = (k < 160) ? (k < IN_DIM ? Wih0[n * IN_DIM + k] : 0.f)
                            : Whh0[n * HDIM + (k - 160)];
        wsf[idx] = (f16)v;
    } else if (idx < E0 + E1) {
        int i2 = idx - E0;
        int e = i2 & 7, l = (i2 >> 3) & 63, fi = i2 >> 9;
        int nt = fi & 63, ks = fi >> 6;
        int k = ks * 32 + ((l >> 4) << 3) + e;
        int n = nt * 16 + (l & 15);
        float v = (k < HDIM) ? Wih1[n * HDIM + k] : Whh1[n * HDIM + (k - HDIM)];
        wsf[idx] = (f16)v;
    } else if (idx < F16TOT) {
        int i3 = idx - (E0 + E1);
        int e = i3 & 7, l = (i3 >> 3) & 63, fi = i3 >> 9;
        int nt = fi & 15, ks = fi >> 4;
        int k = ks * 32 + ((l >> 4) << 3) + e;
        int j = nt * 16 + (l & 15);
        wsf[idx] = (f16)Wa1[j * HDIM + k];
    } else if (idx < PREP_TOT) {
        int i4 = idx - F16TOT;
        if (i4 < 1024) wsb[i4] = bih0[i4] + bhh0[i4];
        else           wsb[i4] = bih1[i4 - 1024] + bhh1[i4 - 1024];
    }
}

__global__ __launch_bounds__(NTHR, 2) void lstm_mfma(
    const float* __restrict__ x, const f16* __restrict__ wsf,
    const float* __restrict__ wsb, const float* __restrict__ Wa2,
    const float* __restrict__ ba1, const float* __restrict__ ba2,
    float* __restrict__ out)
{
    __shared__ __align__(16) f16 A[16][ACOLS];
    __shared__ float red[8][16];

    const int tid = threadIdx.x;
    const int l   = tid & 63;
    const int w   = tid >> 6;         // wave 0..7
    const int lm  = l & 15;           // A-row / C-col(n) lane coord
    const int lk  = (l >> 4) << 3;    // k-offset within a 32-slice
    const int m0  = (l >> 4) << 2;    // C rows m0..m0+3
    const int row0 = blockIdx.x * 16;

    const f16x8* B0 = (const f16x8*)(wsf);
    const f16x8* B1 = (const f16x8*)(wsf + E0);
    const f16x8* BA = (const f16x8*)(wsf + E0 + E1);

    // zero the activation tile (x pad cols + h0 + h1)
    for (int i = tid; i < 16 * ACOLS; i += NTHR) ((f16*)A)[i] = (f16)0.f;

    // per-thread constants
    const int u0 = (2 * w) * 16 + lm;       // first unit / adv-j
    const int u1 = (2 * w + 1) * 16 + lm;   // second
    float b0v[2][4], b1v[2][4];
    #pragma unroll
    for (int g = 0; g < 4; g++) {
        b0v[0][g] = wsb[g * 256 + u0];  b0v[1][g] = wsb[g * 256 + u1];
        b1v[0][g] = wsb[1024 + g * 256 + u0];  b1v[1][g] = wsb[1024 + g * 256 + u1];
    }
    const float bAv[2]  = { ba1[u0], ba1[u1] };
    const float wa2v[2] = { Wa2[u0], Wa2[u1] };
    const float ba2v    = ba2[0];

    float c0s[2][4], c1s[2][4];
    #pragma unroll
    for (int q = 0; q < 2; q++)
        #pragma unroll
        for (int r = 0; r < 4; r++) { c0s[q][r] = 0.f; c1s[q][r] = 0.f; }

    __syncthreads();

    #pragma unroll 1
    for (int t = 0; t < T_STEPS; t++) {
        // ---- stage x_t (fp32 -> fp16) ----
        for (int i = tid; i < 16 * IN_DIM; i += NTHR) {
            int b = i / IN_DIM, k = i - b * IN_DIM;
            A[b][k] = (f16)x[(size_t)(row0 + b) * (T_STEPS * IN_DIM) + (size_t)t * IN_DIM + k];
        }
        __syncthreads();   // B1: x visible (also fences previous step)

        // ================= gates0: C[16x1024] = A[:,0:416] * B0 =================
        f32x4 acc[2][4];
        #pragma unroll
        for (int q = 0; q < 2; q++)
            #pragma unroll
            for (int g = 0; g < 4; g++) {
                float b = b0v[q][g];
                acc[q][g] = (f32x4){b, b, b, b};
            }
        {
            f16x8 bc[8], bn[8];
            #pragma unroll
            for (int g = 0; g < 4; g++)
                #pragma unroll
                for (int q = 0; q < 2; q++)
                    bc[g * 2 + q] = B0[(size_t)(0 * 64 + (g * 16 + 2 * w + q)) * 64 + l];
            for (int ks = 0; ks < NS0; ks++) {
                if (ks + 1 < NS0) {
                    #pragma unroll
                    for (int g = 0; g < 4; g++)
                        #pragma unroll
                        for (int q = 0; q < 2; q++)
                            bn[g * 2 + q] = B0[(size_t)((ks + 1) * 64 + (g * 16 + 2 * w + q)) * 64 + l];
                }
                f16x8 a = *(const f16x8*)&A[lm][ks * 32 + lk];
                #pragma unroll
                for (int g = 0; g < 4; g++)
                    #pragma unroll
                    for (int q = 0; q < 2; q++)
                        acc[q][g] = __builtin_amdgcn_mfma_f32_16x16x32_f16(a, bc[g * 2 + q], acc[q][g], 0, 0, 0);
                #pragma unroll
                for (int i = 0; i < 8; i++) bc[i] = bn[i];
            }
        }
        // epilogue: c0,h0 (registers only)
        f16 hnew[2][4];
        #pragma unroll
        for (int q = 0; q < 2; q++)
            #pragma unroll
            for (int r = 0; r < 4; r++) {
                float ig = sigmoidf_(acc[q][0][r]);
                float fg = sigmoidf_(acc[q][1][r]);
                float gv = tanhf_   (acc[q][2][r]);
                float og = sigmoidf_(acc[q][3][r]);
                float c  = fmaf(fg, c0s[q][r], ig * gv);
                c0s[q][r] = c;
                hnew[q][r] = (f16)(og * tanhf_(c));
            }
        __syncthreads();   // B2: all gates0 reads of A done
        #pragma unroll
        for (int r = 0; r < 4; r++) {
            A[m0 + r][H0COL + u0] = hnew[0][r];
            A[m0 + r][H0COL + u1] = hnew[1][r];
        }
        __syncthreads();   // B3: h0 visible

        // ================= gates1: C[16x1024] = A[:,160:672] * B1 =================
        #pragma unroll
        for (int q = 0; q < 2; q++)
            #pragma unroll
            for (int g = 0; g < 4; g++) {
                float b = b1v[q][g];
                acc[q][g] = (f32x4){b, b, b, b};
            }
        {
            f16x8 bc[8], bn[8];
            #pragma unroll
            for (int g = 0; g < 4; g++)
                #pragma unroll
                for (int q = 0; q < 2; q++)
                    bc[g * 2 + q] = B1[(size_t)(0 * 64 + (g * 16 + 2 * w + q)) * 64 + l];
            for (int ks = 0; ks < NS1; ks++) {
                if (ks + 1 < NS1) {
                    #pragma unroll
                    for (int g = 0; g < 4; g++)
                        #pragma unroll
                        for (int q = 0; q < 2; q++)
                            bn[g * 2 + q] = B1[(size_t)((ks + 1) * 64 + (g * 16 + 2 * w + q)) * 64 + l];
                }
                f16x8 a = *(const f16x8*)&A[lm][H0COL + ks * 32 + lk];
                #pragma unroll
                for (int g = 0; g < 4; g++)
                    #pragma unroll
                    for (int q = 0; q < 2; q++)
                        acc[q][g] = __builtin_amdgcn_mfma_f32_16x16x32_f16(a, bc[g * 2 + q], acc[q][g], 0, 0, 0);
                #pragma unroll
                for (int i = 0; i < 8; i++) bc[i] = bn[i];
            }
        }
        #pragma unroll
        for (int q = 0; q < 2; q++)
            #pragma unroll
            for (int r = 0; r < 4; r++) {
                float ig = sigmoidf_(acc[q][0][r]);
                float fg = sigmoidf_(acc[q][1][r]);
                float gv = tanhf_   (acc[q][2][r]);
                float og = sigmoidf_(acc[q][3][r]);
                float c  = fmaf(fg, c1s[q][r], ig * gv);
                c1s[q][r] = c;
                hnew[q][r] = (f16)(og * tanhf_(c));
            }
        __syncthreads();   // B4: all gates1 reads done
        #pragma unroll
        for (int r = 0; r < 4; r++) {
            A[m0 + r][H1COL + u0] = hnew[0][r];
            A[m0 + r][H1COL + u1] = hnew[1][r];
        }
        __syncthreads();   // B5: h1 visible

        // ================= adv: C[16x256] = A[:,416:672] * BA, relu, dot wa2 =========
        f32x4 accA[2];
        #pragma unroll
        for (int q = 0; q < 2; q++) {
            float b = bAv[q];
            accA[q] = (f32x4){b, b, b, b};
        }
        {
            f16x8 bc[2], bn[2];
            #pragma unroll
            for (int q = 0; q < 2; q++)
                bc[q] = BA[(size_t)(0 * 16 + (2 * w + q)) * 64 + l];
            for (int ks = 0; ks < NSA; ks++) {
                if (ks + 1 < NSA) {
                    #pragma unroll
                    for (int q = 0; q < 2; q++)
                        bn[q] = BA[(size_t)((ks + 1) * 16 + (2 * w + q)) * 64 + l];
                }
                f16x8 a = *(const f16x8*)&A[lm][H1COL + ks * 32 + lk];
                #pragma unroll
                for (int q = 0; q < 2; q++)
                    accA[q] = __builtin_amdgcn_mfma_f32_16x16x32_f16(a, bc[q], accA[q], 0, 0, 0);
                bc[0] = bn[0]; bc[1] = bn[1];
            }
        }
        float s[4];
        #pragma unroll
        for (int r = 0; r < 4; r++)
            s[r] = fmaxf(accA[0][r], 0.f) * wa2v[0] + fmaxf(accA[1][r], 0.f) * wa2v[1];
        #pragma unroll
        for (int msk = 1; msk < 16; msk <<= 1)
            #pragma unroll
            for (int r = 0; r < 4; r++)
                s[r] += __shfl_xor(s[r], msk, 64);
        if (lm == 0) {
            #pragma unroll
            for (int r = 0; r < 4; r++) red[w][m0 + r] = s[r];
        }
        __syncthreads();   // B6: red ready
        if (tid < 16) {
            float o = ba2v;
            #pragma unroll
            for (int w2 = 0; w2 < 8; w2++) o += red[w2][tid];
            out[(size_t)t * BTOT + row0 + tid] = o;
        }
    }
}

extern "C" void kernel_launch(void* const* d_in, const int* in_sizes, int n_in,
                              void* d_out, int out_size, void* d_ws, size_t ws_size,
                              hipStream_t stream)
{
    const float* x    = (const float*)d_in[0];
    const float* Wih0 = (const float*)d_in[1];
    const float* Whh0 = (const float*)d_in[2];
    const float* bih0 = (const float*)d_in[3];
    const float* bhh0 = (const float*)d_in[4];
    const float* Wih1 = (const float*)d_in[5];
    const float* Whh1 = (const float*)d_in[6];
    const float* bih1 = (const float*)d_in[7];
    const float* bhh1 = (const float*)d_in[8];
    const float* Wa1  = (const float*)d_in[9];
    const float* ba1  = (const float*)d_in[10];
    const float* Wa2  = (const float*)d_in[11];
    const float* ba2  = (const float*)d_in[12];

    f16*   wsf = (f16*)d_ws;
    float* wsb = (float*)((char*)d_ws + (size_t)F16TOT * sizeof(f16));
    float* out = (float*)d_out;

    hipLaunchKernelGGL(prep, dim3(PREP_TOT / 256), dim3(256), 0, stream,
                       Wih0, Whh0, bih0, bhh0, Wih1, Whh1, bih1, bhh1, Wa1, wsf, wsb);
    hipLaunchKernelGGL(lstm_mfma, dim3(NBLK), dim3(NTHR), 0, stream,
                       x, wsf, wsb, Wa2, ba1, ba2, out);
}

// Round 4
// 12144.577 us; speedup vs baseline: 2.1474x; 1.0228x over previous
//
#include <hip/hip_runtime.h>
#include <cstdint>
#include <cstddef>

#define T_STEPS 100
#define IN_DIM  140
#define HDIM    256
#define BTOT    4096
#define MROWS   32            // rows per block
#define NBLK    (BTOT/MROWS)  // 128 blocks
#define NTHR    512           // 8 waves

typedef _Float16 f16;
typedef _Float16 f16x8 __attribute__((ext_vector_type(8)));
typedef float    f32x4 __attribute__((ext_vector_type(4)));

// K dims (padded to 32): gates0 K=416 (x 160 incl pad + h0 256), gates1 K=512, adv K=256
#define NS0 13
#define NS1 16
#define NSA 8
// fragment = 64 lanes x 8 f16 = 512 elems = 1KB
#define E0 (NS0*64*512)       // 425984
#define E1 (NS1*64*512)       // 524288
#define EA (NSA*16*512)       // 65536
#define F16TOT (E0+E1+EA)     // 1015808 f16 = ~2MB
#define EB 2048               // 2x1024 fp32 biases
#define PREP_TOT (F16TOT+EB)  // 1017856 = 3976*256

// LDS activation tile: cols 0-159 x(padded), 160-415 h0, 416-671 h1, 672-679 pad
#define ACOLS 680
#define H0COL 160
#define H1COL 416

__device__ __forceinline__ float sigmoidf_(float x) {
    return 1.0f / (1.0f + __expf(-x));
}
__device__ __forceinline__ float tanhf_(float x) {
    return 1.0f - 2.0f / (__expf(2.0f * x) + 1.0f);
}

// Pack weights into MFMA B-fragment order (fp16) + folded fp32 biases.
// Frag (ks, nt): lane l, elem e -> B[k = ks*32 + (l>>4)*8 + e][n = nt*16 + (l&15)]
__global__ void prep(const float* __restrict__ Wih0, const float* __restrict__ Whh0,
                     const float* __restrict__ bih0, const float* __restrict__ bhh0,
                     const float* __restrict__ Wih1, const float* __restrict__ Whh1,
                     const float* __restrict__ bih1, const float* __restrict__ bhh1,
                     const float* __restrict__ Wa1,  f16* __restrict__ wsf,
                     float* __restrict__ wsb)
{
    int idx = blockIdx.x * 256 + threadIdx.x;
    if (idx < E0) {
        int e = idx & 7, l = (idx >> 3) & 63, fi = idx >> 9;
        int nt = fi & 63, ks = fi >> 6;
        int k = ks * 32 + ((l >> 4) << 3) + e;
        int n = nt * 16 + (l & 15);
        float v = (k < 160) ? (k < IN_DIM ? Wih0[n * IN_DIM + k] : 0.f)
                            : Whh0[n * HDIM + (k - 160)];
        wsf[idx] = (f16)v;
    } else if (idx < E0 + E1) {
        int i2 = idx - E0;
        int e = i2 & 7, l = (i2 >> 3) & 63, fi = i2 >> 9;
        int nt = fi & 63, ks = fi >> 6;
        int k = ks * 32 + ((l >> 4) << 3) + e;
        int n = nt * 16 + (l & 15);
        float v = (k < HDIM) ? Wih1[n * HDIM + k] : Whh1[n * HDIM + (k - HDIM)];
        wsf[idx] = (f16)v;
    } else if (idx < F16TOT) {
        int i3 = idx - (E0 + E1);
        int e = i3 & 7, l = (i3 >> 3) & 63, fi = i3 >> 9;
        int nt = fi & 15, ks = fi >> 4;
        int k = ks * 32 + ((l >> 4) << 3) + e;
        int j = nt * 16 + (l & 15);
        wsf[idx] = (f16)Wa1[j * HDIM + k];
    } else if (idx < PREP_TOT) {
        int i4 = idx - F16TOT;
        if (i4 < 1024) wsb[i4] = bih0[i4] + bhh0[i4];
        else           wsb[i4] = bih1[i4 - 1024] + bhh1[i4 - 1024];
    }
}

__global__ __launch_bounds__(NTHR) void lstm_mfma(
    const float* __restrict__ x, const f16* __restrict__ wsf,
    const float* __restrict__ wsb, const float* __restrict__ Wa2,
    const float* __restrict__ ba1, const float* __restrict__ ba2,
    float* __restrict__ out)
{
    __shared__ __align__(16) f16 A[MROWS][ACOLS];
    __shared__ float red[8][MROWS];

    const int tid = threadIdx.x;
    const int l   = tid & 63;
    const int w   = tid >> 6;         // wave 0..7
    const int lm  = l & 15;           // A-row(within m-tile) / C-col(n) lane coord
    const int lk  = (l >> 4) << 3;    // k-offset within a 32-slice
    const int m0  = (l >> 4) << 2;    // C rows m0..m0+3 (within m-tile)
    const int row0 = blockIdx.x * MROWS;

    const f16x8* B0 = (const f16x8*)(wsf);
    const f16x8* B1 = (const f16x8*)(wsf + E0);
    const f16x8* BA = (const f16x8*)(wsf + E0 + E1);

    // zero the activation tile (x pad cols + h0 + h1)
    for (int i = tid; i < MROWS * ACOLS; i += NTHR) ((f16*)A)[i] = (f16)0.f;

    // per-thread constants
    const int u0 = (2 * w) * 16 + lm;       // first unit / adv-j
    const int u1 = (2 * w + 1) * 16 + lm;   // second
    float b0v[2][4], b1v[2][4];
    #pragma unroll
    for (int g = 0; g < 4; g++) {
        b0v[0][g] = wsb[g * 256 + u0];  b0v[1][g] = wsb[g * 256 + u1];
        b1v[0][g] = wsb[1024 + g * 256 + u0];  b1v[1][g] = wsb[1024 + g * 256 + u1];
    }
    const float bAv[2]  = { ba1[u0], ba1[u1] };
    const float wa2v[2] = { Wa2[u0], Wa2[u1] };
    const float ba2v    = ba2[0];

    // c-state: [m-tile][q][r]
    float c0s[2][2][4], c1s[2][2][4];
    #pragma unroll
    for (int mt = 0; mt < 2; mt++)
        #pragma unroll
        for (int q = 0; q < 2; q++)
            #pragma unroll
            for (int r = 0; r < 4; r++) { c0s[mt][q][r] = 0.f; c1s[mt][q][r] = 0.f; }

    __syncthreads();

    #pragma unroll 1
    for (int t = 0; t < T_STEPS; t++) {
        // ---- stage x_t (fp32 -> fp16) ----
        for (int i = tid; i < MROWS * IN_DIM; i += NTHR) {
            int b = i / IN_DIM, k = i - b * IN_DIM;
            A[b][k] = (f16)x[(size_t)(row0 + b) * (T_STEPS * IN_DIM) + (size_t)t * IN_DIM + k];
        }
        __syncthreads();   // B1: x visible (also fences previous step)

        // ================= gates0: C[32x1024] = A[:,0:416] * B0 =================
        f32x4 acc[2][2][4];
        #pragma unroll
        for (int mt = 0; mt < 2; mt++)
            #pragma unroll
            for (int q = 0; q < 2; q++)
                #pragma unroll
                for (int g = 0; g < 4; g++) {
                    float b = b0v[q][g];
                    acc[mt][q][g] = (f32x4){b, b, b, b};
                }
        {
            f16x8 bc[8], bn[8];
            #pragma unroll
            for (int g = 0; g < 4; g++)
                #pragma unroll
                for (int q = 0; q < 2; q++)
                    bc[g * 2 + q] = B0[(size_t)(0 * 64 + (g * 16 + 2 * w + q)) * 64 + l];
            for (int ks = 0; ks < NS0; ks++) {
                if (ks + 1 < NS0) {
                    #pragma unroll
                    for (int g = 0; g < 4; g++)
                        #pragma unroll
                        for (int q = 0; q < 2; q++)
                            bn[g * 2 + q] = B0[(size_t)((ks + 1) * 64 + (g * 16 + 2 * w + q)) * 64 + l];
                }
                f16x8 a0 = *(const f16x8*)&A[lm     ][ks * 32 + lk];
                f16x8 a1 = *(const f16x8*)&A[16 + lm][ks * 32 + lk];
                #pragma unroll
                for (int g = 0; g < 4; g++)
                    #pragma unroll
                    for (int q = 0; q < 2; q++) {
                        acc[0][q][g] = __builtin_amdgcn_mfma_f32_16x16x32_f16(a0, bc[g * 2 + q], acc[0][q][g], 0, 0, 0);
                        acc[1][q][g] = __builtin_amdgcn_mfma_f32_16x16x32_f16(a1, bc[g * 2 + q], acc[1][q][g], 0, 0, 0);
                    }
                #pragma unroll
                for (int i = 0; i < 8; i++) bc[i] = bn[i];
            }
        }
        // epilogue: c0,h0 (registers only)
        f16 hnew[2][2][4];
        #pragma unroll
        for (int mt = 0; mt < 2; mt++)
            #pragma unroll
            for (int q = 0; q < 2; q++)
                #pragma unroll
                for (int r = 0; r < 4; r++) {
                    float ig = sigmoidf_(acc[mt][q][0][r]);
                    float fg = sigmoidf_(acc[mt][q][1][r]);
                    float gv = tanhf_   (acc[mt][q][2][r]);
                    float og = sigmoidf_(acc[mt][q][3][r]);
                    float c  = fmaf(fg, c0s[mt][q][r], ig * gv);
                    c0s[mt][q][r] = c;
                    hnew[mt][q][r] = (f16)(og * tanhf_(c));
                }
        __syncthreads();   // B2: all gates0 reads of A done
        #pragma unroll
        for (int mt = 0; mt < 2; mt++)
            #pragma unroll
            for (int r = 0; r < 4; r++) {
                A[mt * 16 + m0 + r][H0COL + u0] = hnew[mt][0][r];
                A[mt * 16 + m0 + r][H0COL + u1] = hnew[mt][1][r];
            }
        __syncthreads();   // B3: h0 visible

        // ================= gates1: C[32x1024] = A[:,160:672] * B1 =================
        #pragma unroll
        for (int mt = 0; mt < 2; mt++)
            #pragma unroll
            for (int q = 0; q < 2; q++)
                #pragma unroll
                for (int g = 0; g < 4; g++) {
                    float b = b1v[q][g];
                    acc[mt][q][g] = (f32x4){b, b, b, b};
                }
        {
            f16x8 bc[8], bn[8];
            #pragma unroll
            for (int g = 0; g < 4; g++)
                #pragma unroll
                for (int q = 0; q < 2; q++)
                    bc[g * 2 + q] = B1[(size_t)(0 * 64 + (g * 16 + 2 * w + q)) * 64 + l];
            for (int ks = 0; ks < NS1; ks++) {
                if (ks + 1 < NS1) {
                    #pragma unroll
                    for (int g = 0; g < 4; g++)
                        #pragma unroll
                        for (int q = 0; q < 2; q++)
                            bn[g * 2 + q] = B1[(size_t)((ks + 1) * 64 + (g * 16 + 2 * w + q)) * 64 + l];
                }
                f16x8 a0 = *(const f16x8*)&A[lm     ][H0COL + ks * 32 + lk];
                f16x8 a1 = *(const f16x8*)&A[16 + lm][H0COL + ks * 32 + lk];
                #pragma unroll
                for (int g = 0; g < 4; g++)
                    #pragma unroll
                    for (int q = 0; q < 2; q++) {
                        acc[0][q][g] = __builtin_amdgcn_mfma_f32_16x16x32_f16(a0, bc[g * 2 + q], acc[0][q][g], 0, 0, 0);
                        acc[1][q][g] = __builtin_amdgcn_mfma_f32_16x16x32_f16(a1, bc[g * 2 + q], acc[1][q][g], 0, 0, 0);
                    }
                #pragma unroll
                for (int i = 0; i < 8; i++) bc[i] = bn[i];
            }
        }
        #pragma unroll
        for (int mt = 0; mt < 2; mt++)
            #pragma unroll
            for (int q = 0; q < 2; q++)
                #pragma unroll
                for (int r = 0; r < 4; r++) {
                    float ig = sigmoidf_(acc[mt][q][0][r]);
                    float fg = sigmoidf_(acc[mt][q][1][r]);
                    float gv = tanhf_   (acc[mt][q][2][r]);
                    float og = sigmoidf_(acc[mt][q][3][r]);
                    float c  = fmaf(fg, c1s[mt][q][r], ig * gv);
                    c1s[mt][q][r] = c;
                    hnew[mt][q][r] = (f16)(og * tanhf_(c));
                }
        __syncthreads();   // B4: all gates1 reads done
        #pragma unroll
        for (int mt = 0; mt < 2; mt++)
            #pragma unroll
            for (int r = 0; r < 4; r++) {
                A[mt * 16 + m0 + r][H1COL + u0] = hnew[mt][0][r];
                A[mt * 16 + m0 + r][H1COL + u1] = hnew[mt][1][r];
            }
        __syncthreads();   // B5: h1 visible

        // ================= adv: C[32x256] = A[:,416:672] * BA, relu, dot wa2 ======
        f32x4 accA[2][2];
        #pragma unroll
        for (int mt = 0; mt < 2; mt++)
            #pragma unroll
            for (int q = 0; q < 2; q++) {
                float b = bAv[q];
                accA[mt][q] = (f32x4){b, b, b, b};
            }
        {
            f16x8 bc[2], bn[2];
            #pragma unroll
            for (int q = 0; q < 2; q++)
                bc[q] = BA[(size_t)(0 * 16 + (2 * w + q)) * 64 + l];
            for (int ks = 0; ks < NSA; ks++) {
                if (ks + 1 < NSA) {
                    #pragma unroll
                    for (int q = 0; q < 2; q++)
                        bn[q] = BA[(size_t)((ks + 1) * 16 + (2 * w + q)) * 64 + l];
                }
                f16x8 a0 = *(const f16x8*)&A[lm     ][H1COL + ks * 32 + lk];
                f16x8 a1 = *(const f16x8*)&A[16 + lm][H1COL + ks * 32 + lk];
                #pragma unroll
                for (int q = 0; q < 2; q++) {
                    accA[0][q] = __builtin_amdgcn_mfma_f32_16x16x32_f16(a0, bc[q], accA[0][q], 0, 0, 0);
                    accA[1][q] = __builtin_amdgcn_mfma_f32_16x16x32_f16(a1, bc[q], accA[1][q], 0, 0, 0);
                }
                bc[0] = bn[0]; bc[1] = bn[1];
            }
        }
        float s[2][4];
        #pragma unroll
        for (int mt = 0; mt < 2; mt++)
            #pragma unroll
            for (int r = 0; r < 4; r++)
                s[mt][r] = fmaxf(accA[mt][0][r], 0.f) * wa2v[0]
                         + fmaxf(accA[mt][1][r], 0.f) * wa2v[1];
        #pragma unroll
        for (int msk = 1; msk < 16; msk <<= 1)
            #pragma unroll
            for (int mt = 0; mt < 2; mt++)
                #pragma unroll
                for (int r = 0; r < 4; r++)
                    s[mt][r] += __shfl_xor(s[mt][r], msk, 64);
        if (lm == 0) {
            #pragma unroll
            for (int mt = 0; mt < 2; mt++)
                #pragma unroll
                for (int r = 0; r < 4; r++)
                    red[w][mt * 16 + m0 + r] = s[mt][r];
        }
        __syncthreads();   // B6: red ready
        if (tid < MROWS) {
            float o = ba2v;
            #pragma unroll
            for (int w2 = 0; w2 < 8; w2++) o += red[w2][tid];
            out[(size_t)t * BTOT + row0 + tid] = o;
        }
    }
}

extern "C" void kernel_launch(void* const* d_in, const int* in_sizes, int n_in,
                              void* d_out, int out_size, void* d_ws, size_t ws_size,
                              hipStream_t stream)
{
    const float* x    = (const float*)d_in[0];
    const float* Wih0 = (const float*)d_in[1];
    const float* Whh0 = (const float*)d_in[2];
    const float* bih0 = (const float*)d_in[3];
    const float* bhh0 = (const float*)d_in[4];
    const float* Wih1 = (const float*)d_in[5];
    const float* Whh1 = (const float*)d_in[6];
    const float* bih1 = (const float*)d_in[7];
    const float* bhh1 = (const float*)d_in[8];
    const float* Wa1  = (const float*)d_in[9];
    const float* ba1  = (const float*)d_in[10];
    const float* Wa2  = (const float*)d_in[11];
    const float* ba2  = (const float*)d_in[12];

    f16*   wsf = (f16*)d_ws;
    float* wsb = (float*)((char*)d_ws + (size_t)F16TOT * sizeof(f16));
    float* out = (float*)d_out;

    hipLaunchKernelGGL(prep, dim3(PREP_TOT / 256), dim3(256), 0, stream,
                       Wih0, Whh0, bih0, bhh0, Wih1, Whh1, bih1, bhh1, Wa1, wsf, wsb);
    hipLaunchKernelGGL(lstm_mfma, dim3(NBLK), dim3(NTHR), 0, stream,
                       x, wsf, wsb, Wa2, ba1, ba2, out);
}

// Round 5
// 2204.629 us; speedup vs baseline: 11.8296x; 5.5087x over previous
//
#include <hip/hip_runtime.h>
#include <cstdint>
#include <cstddef>

#define T_STEPS 100
#define IN_DIM  140
#define HDIM    256
#define BTOT    4096
#define MROWS   16
#define NBLK    (BTOT/MROWS)  // 256 blocks
#define NTHR    512           // 8 waves

typedef _Float16 f16;
typedef _Float16 f16x8 __attribute__((ext_vector_type(8)));
typedef float    f32x4 __attribute__((ext_vector_type(4)));

// K dims (padded to 32): gates0 K=416 (x 160 incl pad + h0 256), gates1 K=512, adv K=256
#define NS0 13
#define NS1 16
#define NSA 8
// fragment = 64 lanes x 8 f16 = 512 elems = 1KB
#define E0 (NS0*64*512)       // 425984
#define E1 (NS1*64*512)       // 524288
#define EA (NSA*16*512)       // 65536
#define F16TOT (E0+E1+EA)     // 1015808 f16 = ~2MB
#define EB 2048               // 2x1024 fp32 biases
#define PREP_TOT (F16TOT+EB)  // 1017856 = 3976*256

// LDS activation tile: cols 0-159 x(padded), 160-415 h0, 416-671 h1, 672-679 pad
#define ACOLS 680
#define H0COL 160
#define H1COL 416

__device__ __forceinline__ float sigmoidf_(float x) {
    return 1.0f / (1.0f + __expf(-x));
}
__device__ __forceinline__ float tanhf_(float x) {
    return 1.0f - 2.0f / (__expf(2.0f * x) + 1.0f);
}

// Pack weights into MFMA B-fragment order (fp16) + folded fp32 biases.
// Frag (ks, nt): lane l, elem e -> B[k = ks*32 + (l>>4)*8 + e][n = nt*16 + (l&15)]
__global__ void prep(const float* __restrict__ Wih0, const float* __restrict__ Whh0,
                     const float* __restrict__ bih0, const float* __restrict__ bhh0,
                     const float* __restrict__ Wih1, const float* __restrict__ Whh1,
                     const float* __restrict__ bih1, const float* __restrict__ bhh1,
                     const float* __restrict__ Wa1,  f16* __restrict__ wsf,
                     float* __restrict__ wsb)
{
    int idx = blockIdx.x * 256 + threadIdx.x;
    if (idx < E0) {
        int e = idx & 7, l = (idx >> 3) & 63, fi = idx >> 9;
        int nt = fi & 63, ks = fi >> 6;
        int k = ks * 32 + ((l >> 4) << 3) + e;
        int n = nt * 16 + (l & 15);
        float v = (k < 160) ? (k < IN_DIM ? Wih0[n * IN_DIM + k] : 0.f)
                            : Whh0[n * HDIM + (k - 160)];
        wsf[idx] = (f16)v;
    } else if (idx < E0 + E1) {
        int i2 = idx - E0;
        int e = i2 & 7, l = (i2 >> 3) & 63, fi = i2 >> 9;
        int nt = fi & 63, ks = fi >> 6;
        int k = ks * 32 + ((l >> 4) << 3) + e;
        int n = nt * 16 + (l & 15);
        float v = (k < HDIM) ? Wih1[n * HDIM + k] : Whh1[n * HDIM + (k - HDIM)];
        wsf[idx] = (f16)v;
    } else if (idx < F16TOT) {
        int i3 = idx - (E0 + E1);
        int e = i3 & 7, l = (i3 >> 3) & 63, fi = i3 >> 9;
        int nt = fi & 15, ks = fi >> 4;
        int k = ks * 32 + ((l >> 4) << 3) + e;
        int j = nt * 16 + (l & 15);
        wsf[idx] = (f16)Wa1[j * HDIM + k];
    } else if (idx < PREP_TOT) {
        int i4 = idx - F16TOT;
        if (i4 < 1024) wsb[i4] = bih0[i4] + bhh0[i4];
        else           wsb[i4] = bih1[i4 - 1024] + bhh1[i4 - 1024];
    }
}

#define GLOAD_LDS(gsrc, ldst)                                              \
    __builtin_amdgcn_global_load_lds(                                      \
        (const __attribute__((address_space(1))) void*)(gsrc),             \
        (__attribute__((address_space(3))) void*)(ldst), 16, 0, 0)

// Stage this wave's 8 fragments (gates sections, NT=64) of one k-slice.
// slice = wsf + ks*64*512 (contiguous 64KB). Wave w's frags: g*16+2w+q.
__device__ __forceinline__ void stage8(const f16* slice, f16* dst, int w, int l) {
    #pragma unroll
    for (int g = 0; g < 4; g++)
        #pragma unroll
        for (int q = 0; q < 2; q++) {
            const f16* src = slice + (size_t)(g * 16 + 2 * w + q) * 512 + l * 8;
            GLOAD_LDS(src, dst + (g * 2 + q) * 512);
        }
}

// Stage this wave's 2 fragments (adv section, NT=16) of one k-slice.
__device__ __forceinline__ void stage2(const f16* slice, f16* dst, int w, int l) {
    #pragma unroll
    for (int q = 0; q < 2; q++) {
        const f16* src = slice + (size_t)(2 * w + q) * 512 + l * 8;
        GLOAD_LDS(src, dst + q * 512);
    }
}

#define WAIT_LGKM0 do { asm volatile("s_waitcnt lgkmcnt(0)" ::: "memory"); \
                        __builtin_amdgcn_sched_barrier(0); } while (0)
#define WAIT_VM(N) do { asm volatile("s_waitcnt vmcnt(" #N ")" ::: "memory"); \
                        __builtin_amdgcn_sched_barrier(0); } while (0)

__global__ __launch_bounds__(NTHR) void lstm_mfma(
    const float* __restrict__ x, const f16* __restrict__ wsf,
    const float* __restrict__ wsb, const float* __restrict__ Wa2,
    const float* __restrict__ ba1, const float* __restrict__ ba2,
    float* __restrict__ out)
{
    __shared__ __align__(16) f16 A[MROWS][ACOLS];       // 21760 B
    __shared__ __align__(16) f16 Bst[8][2][4096];       // 8 waves x 2 bufs x 8KB = 128KB
    __shared__ float red[8][MROWS];                     // 512 B

    const int tid = threadIdx.x;
    const int l   = tid & 63;
    const int w   = tid >> 6;         // wave 0..7
    const int lm  = l & 15;           // A-row / C-col(n) lane coord
    const int lk  = (l >> 4) << 3;    // k-offset within a 32-slice
    const int m0  = (l >> 4) << 2;    // C rows m0..m0+3
    const int row0 = blockIdx.x * MROWS;

    const f16* W0 = wsf;
    const f16* W1 = wsf + E0;
    const f16* WA = wsf + E0 + E1;
    f16* wb0 = &Bst[w][0][0];
    f16* wb1 = &Bst[w][1][0];

    // zero activation tile
    for (int i = tid; i < MROWS * ACOLS; i += NTHR) ((f16*)A)[i] = (f16)0.f;

    const int u0 = (2 * w) * 16 + lm;
    const int u1 = (2 * w + 1) * 16 + lm;
    float b0v[2][4], b1v[2][4];
    #pragma unroll
    for (int g = 0; g < 4; g++) {
        b0v[0][g] = wsb[g * 256 + u0];          b0v[1][g] = wsb[g * 256 + u1];
        b1v[0][g] = wsb[1024 + g * 256 + u0];   b1v[1][g] = wsb[1024 + g * 256 + u1];
    }
    const float bAv[2]  = { ba1[u0], ba1[u1] };
    const float wa2v[2] = { Wa2[u0], Wa2[u1] };
    const float ba2v    = ba2[0];

    float c0s[2][4], c1s[2][4];
    #pragma unroll
    for (int q = 0; q < 2; q++)
        #pragma unroll
        for (int r = 0; r < 4; r++) { c0s[q][r] = 0.f; c1s[q][r] = 0.f; }

    __syncthreads();

    #pragma unroll 1
    for (int t = 0; t < T_STEPS; t++) {
        // ---- stage x_t (fp32 -> fp16) ----
        for (int i = tid; i < MROWS * IN_DIM; i += NTHR) {
            int b = i / IN_DIM, k = i - b * IN_DIM;
            A[b][k] = (f16)x[(size_t)(row0 + b) * (T_STEPS * IN_DIM) + (size_t)t * IN_DIM + k];
        }
        __syncthreads();   // B1: x visible; vmcnt drained -> clean accounting

        // ================= gates0: C[16x1024] = A[:,0:416] * W0 =================
        f32x4 acc[2][4];
        #pragma unroll
        for (int q = 0; q < 2; q++)
            #pragma unroll
            for (int g = 0; g < 4; g++) {
                float b = b0v[q][g];
                acc[q][g] = (f32x4){b, b, b, b};
            }
        stage8(W0, wb0, w, l);                 // slice 0 -> buf0
        #pragma unroll 1
        for (int ks = 0; ks < NS0; ks++) {
            WAIT_LGKM0;                        // prev ds_reads done before overwrite
            if (ks + 1 < NS0) {
                stage8(W0 + (size_t)(ks + 1) * 64 * 512, (ks & 1) ? wb0 : wb1, w, l);
                WAIT_VM(8);                    // slice ks resident (8 newer in flight)
            } else {
                WAIT_VM(0);
            }
            const f16* rb = (ks & 1) ? wb1 : wb0;
            f16x8 a0 = *(const f16x8*)&A[lm][ks * 32 + lk];
            #pragma unroll
            for (int g = 0; g < 4; g++)
                #pragma unroll
                for (int q = 0; q < 2; q++) {
                    f16x8 bf = *(const f16x8*)(rb + (g * 2 + q) * 512 + l * 8);
                    acc[q][g] = __builtin_amdgcn_mfma_f32_16x16x32_f16(a0, bf, acc[q][g], 0, 0, 0);
                }
        }
        // prefetch gates1 slice 0 early (hides under epilogue + barriers)
        stage8(W1, wb0, w, l);

        f16 hnew[2][4];
        #pragma unroll
        for (int q = 0; q < 2; q++)
            #pragma unroll
            for (int r = 0; r < 4; r++) {
                float ig = sigmoidf_(acc[q][0][r]);
                float fg = sigmoidf_(acc[q][1][r]);
                float gv = tanhf_   (acc[q][2][r]);
                float og = sigmoidf_(acc[q][3][r]);
                float c  = fmaf(fg, c0s[q][r], ig * gv);
                c0s[q][r] = c;
                hnew[q][r] = (f16)(og * tanhf_(c));
            }
        __syncthreads();   // B2: all gates0 A-reads done
        #pragma unroll
        for (int r = 0; r < 4; r++) {
            A[m0 + r][H0COL + u0] = hnew[0][r];
            A[m0 + r][H0COL + u1] = hnew[1][r];
        }
        __syncthreads();   // B3: h0 visible (drains vmcnt -> slice0 of gates1 resident)

        // ================= gates1: C[16x1024] = A[:,160:672] * W1 =================
        #pragma unroll
        for (int q = 0; q < 2; q++)
            #pragma unroll
            for (int g = 0; g < 4; g++) {
                float b = b1v[q][g];
                acc[q][g] = (f32x4){b, b, b, b};
            }
        #pragma unroll 1
        for (int ks = 0; ks < NS1; ks++) {
            WAIT_LGKM0;
            if (ks + 1 < NS1) {
                stage8(W1 + (size_t)(ks + 1) * 64 * 512, (ks & 1) ? wb0 : wb1, w, l);
                WAIT_VM(8);
            } else {
                WAIT_VM(0);
            }
            const f16* rb = (ks & 1) ? wb1 : wb0;
            f16x8 a0 = *(const f16x8*)&A[lm][H0COL + ks * 32 + lk];
            #pragma unroll
            for (int g = 0; g < 4; g++)
                #pragma unroll
                for (int q = 0; q < 2; q++) {
                    f16x8 bf = *(const f16x8*)(rb + (g * 2 + q) * 512 + l * 8);
                    acc[q][g] = __builtin_amdgcn_mfma_f32_16x16x32_f16(a0, bf, acc[q][g], 0, 0, 0);
                }
        }
        // prefetch adv slice 0 early
        stage2(WA, wb0, w, l);

        #pragma unroll
        for (int q = 0; q < 2; q++)
            #pragma unroll
            for (int r = 0; r < 4; r++) {
                float ig = sigmoidf_(acc[q][0][r]);
                float fg = sigmoidf_(acc[q][1][r]);
                float gv = tanhf_   (acc[q][2][r]);
                float og = sigmoidf_(acc[q][3][r]);
                float c  = fmaf(fg, c1s[q][r], ig * gv);
                c1s[q][r] = c;
                hnew[q][r] = (f16)(og * tanhf_(c));
            }
        __syncthreads();   // B4: all gates1 A-reads done
        #pragma unroll
        for (int r = 0; r < 4; r++) {
            A[m0 + r][H1COL + u0] = hnew[0][r];
            A[m0 + r][H1COL + u1] = hnew[1][r];
        }
        __syncthreads();   // B5: h1 visible (drains vmcnt -> adv slice0 resident)

        // ================= adv: C[16x256] = A[:,416:672] * WA ====================
        f32x4 accA[2];
        #pragma unroll
        for (int q = 0; q < 2; q++) {
            float b = bAv[q];
            accA[q] = (f32x4){b, b, b, b};
        }
        #pragma unroll 1
        for (int ks = 0; ks < NSA; ks++) {
            WAIT_LGKM0;
            if (ks + 1 < NSA) {
                stage2(WA + (size_t)(ks + 1) * 16 * 512, (ks & 1) ? wb0 : wb1, w, l);
                WAIT_VM(2);
            } else {
                WAIT_VM(0);
            }
            const f16* rb = (ks & 1) ? wb1 : wb0;
            f16x8 a0 = *(const f16x8*)&A[lm][H1COL + ks * 32 + lk];
            #pragma unroll
            for (int q = 0; q < 2; q++) {
                f16x8 bf = *(const f16x8*)(rb + q * 512 + l * 8);
                accA[q] = __builtin_amdgcn_mfma_f32_16x16x32_f16(a0, bf, accA[q], 0, 0, 0);
            }
        }
        float s[4];
        #pragma unroll
        for (int r = 0; r < 4; r++)
            s[r] = fmaxf(accA[0][r], 0.f) * wa2v[0] + fmaxf(accA[1][r], 0.f) * wa2v[1];
        #pragma unroll
        for (int msk = 1; msk < 16; msk <<= 1)
            #pragma unroll
            for (int r = 0; r < 4; r++)
                s[r] += __shfl_xor(s[r], msk, 64);
        if (lm == 0) {
            #pragma unroll
            for (int r = 0; r < 4; r++) red[w][m0 + r] = s[r];
        }
        __syncthreads();   // B6: red ready; all adv A-reads done
        if (tid < MROWS) {
            float o = ba2v;
            #pragma unroll
            for (int w2 = 0; w2 < 8; w2++) o += red[w2][tid];
            out[(size_t)t * BTOT + row0 + tid] = o;
        }
    }
}

extern "C" void kernel_launch(void* const* d_in, const int* in_sizes, int n_in,
                              void* d_out, int out_size, void* d_ws, size_t ws_size,
                              hipStream_t stream)
{
    const float* x    = (const float*)d_in[0];
    const float* Wih0 = (const float*)d_in[1];
    const float* Whh0 = (const float*)d_in[2];
    const float* bih0 = (const float*)d_in[3];
    const float* bhh0 = (const float*)d_in[4];
    const float* Wih1 = (const float*)d_in[5];
    const float* Whh1 = (const float*)d_in[6];
    const float* bih1 = (const float*)d_in[7];
    const float* bhh1 = (const float*)d_in[8];
    const float* Wa1  = (const float*)d_in[9];
    const float* ba1  = (const float*)d_in[10];
    const float* Wa2  = (const float*)d_in[11];
    const float* ba2  = (const float*)d_in[12];

    f16*   wsf = (f16*)d_ws;
    float* wsb = (float*)((char*)d_ws + (size_t)F16TOT * sizeof(f16));
    float* out = (float*)d_out;

    hipLaunchKernelGGL(prep, dim3(PREP_TOT / 256), dim3(256), 0, stream,
                       Wih0, Whh0, bih0, bhh0, Wih1, Whh1, bih1, bhh1, Wa1, wsf, wsb);
    hipLaunchKernelGGL(lstm_mfma, dim3(NBLK), dim3(NTHR), 0, stream,
                       x, wsf, wsb, Wa2, ba1, ba2, out);
}